// Round 7
// baseline (174.312 us; speedup 1.0000x reference)
//
#include <hip/hip_runtime.h>

// EndEffectorLoss R14: register-file staging, zero LDS pipeline, per-lane rows.
//
// R7-R13 meta-analysis: every variant (sync LDS, async DMA, 3 geometries)
// lands at 1.4-1.7 TB/s HBM and 43-59us. Occupancy is structurally capped by
// the grid (2048 waves = 8/CU = 25%), and the LDS-staged pipeline is at the
// LDS CAPACITY wall: depth2 x 8 waves x 9.2KB/stage = 147KB of 160KB. Deeper
// prefetch through LDS is impossible -> bytes-in-flight/CU capped -> BW capped.
// R14 stages through the REGISTER FILE (2MB/CU, 13x LDS): each lane owns one
// (frame,pose), reads its 864B row as sequential float4s (9/stage, double-
// buffered in regs), FK consumes directly. Column-order reads reuse each 64B
// line across 4 adjacent wave-instrs (4KB inter-touch set -> L1 absorbs, FETCH
// ~1x). No barriers, no vmcnt choreography, no LDS coupling; loads of stage
// k+1 overlap FK(k) via natural scheduling (R7 proved the compiler hoists).
// A/B exchange: adjacent lanes (even=A, odd=B), one __shfl_xor(.,1).
// VGPR<=256 is free (grid ceiling is 2 waves/SIMD) -> __launch_bounds__(256)
// single-arg; no cap -> no R8/R10-style spills.

struct V3 { float x, y, z; };
struct M3 { float m[3][3]; };   // row r = basis vector b_r (row-stacked)
struct FK { M3 o; V3 p; };

__device__ __forceinline__ V3 matvec(const M3& A, const V3& v) {
    return { A.m[0][0]*v.x + A.m[0][1]*v.y + A.m[0][2]*v.z,
             A.m[1][0]*v.x + A.m[1][1]*v.y + A.m[1][2]*v.z,
             A.m[2][0]*v.x + A.m[2][1]*v.y + A.m[2][2]*v.z };
}

__device__ __forceinline__ M3 matmul(const M3& A, const M3& B) {
    M3 C;
#pragma unroll
    for (int i = 0; i < 3; i++)
#pragma unroll
        for (int j = 0; j < 3; j++)
            C.m[i][j] = A.m[i][0]*B.m[0][j] + A.m[i][1]*B.m[1][j] + A.m[i][2]*B.m[2][j];
    return C;
}

// Gram-Schmidt from 6 scalars (matches jnp reference, f32).
__device__ __forceinline__ M3 rot6d(float v0, float v1, float v2,
                                    float v3, float v4, float v5) {
    float n1 = v0*v0 + v1*v1 + v2*v2;
    float r1 = 1.0f / sqrtf(n1);
    V3 b1 = { v0*r1, v1*r1, v2*r1 };
    float d = b1.x*v3 + b1.y*v4 + b1.z*v5;
    V3 u = { v3 - d*b1.x, v4 - d*b1.y, v5 - d*b1.z };
    float n2 = u.x*u.x + u.y*u.y + u.z*u.z;
    float r2 = 1.0f / sqrtf(n2);
    V3 b2 = { u.x*r2, u.y*r2, u.z*r2 };
    V3 b3 = { b1.y*b2.z - b1.z*b2.y, b1.z*b2.x - b1.x*b2.z, b1.x*b2.y - b1.y*b2.x };
    M3 R;
    R.m[0][0]=b1.x; R.m[0][1]=b1.y; R.m[0][2]=b1.z;
    R.m[1][0]=b2.x; R.m[1][1]=b2.y; R.m[1][2]=b2.z;
    R.m[2][0]=b3.x; R.m[2][1]=b3.y; R.m[2][2]=b3.z;
    return R;
}

__device__ __forceinline__ FK fk_step(float a0,float a1,float a2,float a3,float a4,float a5,
                                      float ox,float oy,float oz, const FK& par) {
    V3 t = matvec(par.o, {ox, oy, oz});
    FK s;
    s.p = { par.p.x + t.x, par.p.y + t.y, par.p.z + t.z };
    s.o = matmul(par.o, rot6d(a0, a1, a2, a3, a4, a5));
    return s;
}

__device__ __forceinline__ V3 fk_end(float ox, float oy, float oz, const FK& par) {
    V3 t = matvec(par.o, {ox, oy, oz});
    return { par.p.x + t.x, par.p.y + t.y, par.p.z + t.z };
}

// Load one FK stage (24 pose floats + 12 off floats) of THIS lane's row into
// the named register buffer (prefix X in {a,b}). All addrs 16B-aligned:
// pose quad c of stage ST at P + ST*24 + c*4; off quad c at O + ST*12 + c*4.
#define LOADST(X, ST) do { \
    X##q0 = *(const float4*)(P + (ST)*24 +  0); \
    X##q1 = *(const float4*)(P + (ST)*24 +  4); \
    X##q2 = *(const float4*)(P + (ST)*24 +  8); \
    X##q3 = *(const float4*)(P + (ST)*24 + 12); \
    X##q4 = *(const float4*)(P + (ST)*24 + 16); \
    X##q5 = *(const float4*)(P + (ST)*24 + 20); \
    X##r0 = *(const float4*)(O + (ST)*12 +  0); \
    X##r1 = *(const float4*)(O + (ST)*12 +  4); \
    X##r2 = *(const float4*)(O + (ST)*12 +  8); \
} while (0)

// Joint jj in {0..3} of a staged buffer X: pose floats 6jj..6jj+5, off 3jj..3jj+2.
#define JR0(X) X##q0.x,X##q0.y,X##q0.z,X##q0.w,X##q1.x,X##q1.y
#define JR1(X) X##q1.z,X##q1.w,X##q2.x,X##q2.y,X##q2.z,X##q2.w
#define JR2(X) X##q3.x,X##q3.y,X##q3.z,X##q3.w,X##q4.x,X##q4.y
#define JR3(X) X##q4.z,X##q4.w,X##q5.x,X##q5.y,X##q5.z,X##q5.w
#define JO0(X) X##r0.x,X##r0.y,X##r0.z
#define JO1(X) X##r0.w,X##r1.x,X##r1.y
#define JO2(X) X##r1.z,X##r1.w,X##r2.x
#define JO3(X) X##r2.y,X##r2.z,X##r2.w

__global__ __launch_bounds__(256)
void ee_loss_kernel(const float* __restrict__ poseA, const float* __restrict__ poseB,
                    const float* __restrict__ offA,  const float* __restrict__ offB,
                    const float* __restrict__ tA,    const float* __restrict__ tB,
                    float* __restrict__ out, float inv_count) {
    __shared__ float s_inv[6];
    __shared__ float s_d[15];

    const int tid  = threadIdx.x;
    const long long t = (long long)blockIdx.x * 256 + tid;   // 0..131071
    const int  isB = (int)(t & 1);       // even lane = pose A, odd = pose B
    const long long f = t >> 1;          // frame index

    const float* __restrict__ P = (isB ? poseB : poseA) + f * 144;
    const float* __restrict__ O = (isB ? offB  : offA ) + f * 72;

    // ---- t_pose constants (tiny; consumed after the single barrier) ----
    if (tid < 6) {
        const float* tp = (tid < 3) ? tA : tB;
        int ax = (tid < 3) ? tid : tid - 3;
        float mn = tp[ax], mx = mn;
#pragma unroll
        for (int j = 1; j < 24; j++) {
            float v = tp[j*3 + ax];
            mn = fminf(mn, v); mx = fmaxf(mx, v);
        }
        s_inv[tid] = 1.0f / (mx - mn);
    }
    if (tid < 15) {
        const int EE[5] = {10, 11, 15, 22, 23};
        int e = tid / 3, ax = tid - 3*e;
        int j = EE[e];
        float mnA = tA[ax], mxA = mnA, mnB = tB[ax], mxB = mnB;
#pragma unroll
        for (int k = 1; k < 24; k++) {
            float a = tA[k*3 + ax], b = tB[k*3 + ax];
            mnA = fminf(mnA, a); mxA = fmaxf(mxA, a);
            mnB = fminf(mnB, b); mxB = fmaxf(mxB, b);
        }
        s_d[tid] = tB[j*3 + ax]/(mxB - mnB) - tA[j*3 + ax]/(mxA - mnA);
    }

    float4 aq0, aq1, aq2, aq3, aq4, aq5, ar0, ar1, ar2;
    float4 bq0, bq1, bq2, bq3, bq4, bq5, br0, br1, br2;

    // ---- prologue: stages 0 (buf a) and 1 (buf b) in flight ----
    LOADST(a, 0);
    LOADST(b, 1);

    // ---- stage 0 (joints 0..3) ----
    FK s0; s0.o = rot6d(JR0(a)); s0.p = { ar0.x, ar0.y, ar0.z };
    FK s1 = fk_step(JR1(a), JO1(a), s0);
    FK s2 = fk_step(JR2(a), JO2(a), s0);
    FK s3 = fk_step(JR3(a), JO3(a), s0);
    LOADST(a, 2);                        // overlaps stage-1 compute

    // ---- stage 1 (joints 4..7; parents 1,2,3,4) ----
    FK s4 = fk_step(JR0(b), JO0(b), s1);
    FK s5 = fk_step(JR1(b), JO1(b), s2);
    FK s6 = fk_step(JR2(b), JO2(b), s3);
    FK s7 = fk_step(JR3(b), JO3(b), s4);
    LOADST(b, 3);

    // ---- stage 2 (joints 8..11; parents 5,6,7,8; 10,11 end sites) ----
    FK s8 = fk_step(JR0(a), JO0(a), s5);
    FK s9 = fk_step(JR1(a), JO1(a), s6);
    V3 e10 = fk_end(JO2(a), s7);
    V3 e11 = fk_end(JO3(a), s8);
    LOADST(a, 4);

    // ---- stage 3 (joints 12..15; parents 9,9,9,12; 15 end site) ----
    FK s12 = fk_step(JR0(b), JO0(b), s9);
    FK s13 = fk_step(JR1(b), JO1(b), s9);
    FK s14 = fk_step(JR2(b), JO2(b), s9);
    V3 e15 = fk_end(JO3(b), s12);
    LOADST(b, 5);

    // ---- stage 4 (joints 16..19; parents 13,14,16,17) ----
    FK s16 = fk_step(JR0(a), JO0(a), s13);
    FK s17 = fk_step(JR1(a), JO1(a), s14);
    FK s18 = fk_step(JR2(a), JO2(a), s16);
    FK s19 = fk_step(JR3(a), JO3(a), s17);

    // ---- stage 5 (joints 20..23; parents 18,19,20,21; 22,23 end sites) ----
    FK s20 = fk_step(JR0(b), JO0(b), s18);
    FK s21 = fk_step(JR1(b), JO1(b), s19);
    V3 e22 = fk_end(JO2(b), s20);
    V3 e23 = fk_end(JO3(b), s21);

    // ---- A<->B exchange between adjacent lanes ----
    float p0  = __shfl_xor(e10.x, 1, 64);
    float p1  = __shfl_xor(e10.y, 1, 64);
    float p2  = __shfl_xor(e10.z, 1, 64);
    float p3  = __shfl_xor(e11.x, 1, 64);
    float p4  = __shfl_xor(e11.y, 1, 64);
    float p5  = __shfl_xor(e11.z, 1, 64);
    float p6  = __shfl_xor(e15.x, 1, 64);
    float p7  = __shfl_xor(e15.y, 1, 64);
    float p8  = __shfl_xor(e15.z, 1, 64);
    float p9  = __shfl_xor(e22.x, 1, 64);
    float p10 = __shfl_xor(e22.y, 1, 64);
    float p11 = __shfl_xor(e22.z, 1, 64);
    float p12 = __shfl_xor(e23.x, 1, 64);
    float p13 = __shfl_xor(e23.y, 1, 64);
    float p14 = __shfl_xor(e23.z, 1, 64);

    __syncthreads();                     // s_inv / s_d ready (only barrier)

    float local = 0.0f;
    if (!isB) {                          // even lanes hold A; p* hold B's ee
        const float iax = s_inv[0], iay = s_inv[1], iaz = s_inv[2];
        const float ibx = s_inv[3], iby = s_inv[4], ibz = s_inv[5];
        float t0  = e10.x*iax - p0 *ibx + s_d[ 0];
        float t1  = e10.y*iay - p1 *iby + s_d[ 1];
        float t2  = e10.z*iaz - p2 *ibz + s_d[ 2];
        float t3  = e11.x*iax - p3 *ibx + s_d[ 3];
        float t4  = e11.y*iay - p4 *iby + s_d[ 4];
        float t5  = e11.z*iaz - p5 *ibz + s_d[ 5];
        float t6  = e15.x*iax - p6 *ibx + s_d[ 6];
        float t7  = e15.y*iay - p7 *iby + s_d[ 7];
        float t8  = e15.z*iaz - p8 *ibz + s_d[ 8];
        float t9  = e22.x*iax - p9 *ibx + s_d[ 9];
        float t10 = e22.y*iay - p10*iby + s_d[10];
        float t11 = e22.z*iaz - p11*ibz + s_d[11];
        float t12 = e23.x*iax - p12*ibx + s_d[12];
        float t13 = e23.y*iay - p13*iby + s_d[13];
        float t14 = e23.z*iaz - p14*ibz + s_d[14];
        local = ((t0*t0 + t1*t1) + (t2*t2 + t3*t3) + (t4*t4 + t5*t5) +
                 (t6*t6 + t7*t7) + (t8*t8 + t9*t9) + (t10*t10 + t11*t11) +
                 (t12*t12 + t13*t13) + t14*t14) * inv_count;
    }
    // full-wave reduce (odd lanes contribute 0); one atomic per wave.
#pragma unroll
    for (int off = 32; off > 0; off >>= 1)
        local += __shfl_down(local, off, 64);
    if ((tid & 63) == 0) atomicAdd(out, local);
}

extern "C" void kernel_launch(void* const* d_in, const int* in_sizes, int n_in,
                              void* d_out, int out_size, void* d_ws, size_t ws_size,
                              hipStream_t stream) {
    const float* poseA = (const float*)d_in[0];
    const float* poseB = (const float*)d_in[1];
    const float* offA  = (const float*)d_in[2];
    const float* offB  = (const float*)d_in[3];
    const float* tA    = (const float*)d_in[4];
    const float* tB    = (const float*)d_in[5];
    float* out = (float*)d_out;

    const int F = in_sizes[0] / 144;          // 65536
    const int blocks = (2 * F) / 256;         // 512 blocks, one lane per (frame,pose)
    const float inv_count = 1.0f / ((float)F * 15.0f);

    hipMemsetAsync(out, 0, sizeof(float), stream);
    ee_loss_kernel<<<blocks, 256, 0, stream>>>(poseA, poseB, offA, offB, tA, tB,
                                               out, inv_count);
}